// Round 7
// baseline (306.739 us; speedup 1.0000x reference)
//
#include <hip/hip_runtime.h>

#define HH 384
#define WW 384
#define HWSZ (HH * WW)          // 147456
#define NPLANES 128             // 2 batch * 64 chan
#define CHN 64
#define VSTRIPS 4
#define STRIP_H 96              // HH / VSTRIPS
#define RING 48                 // LDS ring rows (72 KB)
#define NACC 11
#define NSUPER 22               // 16 compute groups + 6 lag
#define QP (HWSZ / 4)           // 36864 float4 per plane
#define NINQ (NPLANES * QP)     // 4,718,592 input quads
#define OB 2048                 // out blocks: 8 per CU exactly
#define OT 256
#define OITER (NINQ / (OB * OT))   // 9, exact

typedef float f4 __attribute__((ext_vector_type(4)));

// One block = one (plane, 96-row strip): row prefix sums in LDS ring,
// vertical running box sums in registers, 11 moment accumulators.
__global__ __launch_bounds__(384, 3) void stats_fused(const float* __restrict__ x,
                                                      float* __restrict__ partials) {
    __shared__ float ring[RING][WW];      // inclusive row prefix sums
    __shared__ float redbuf[6 * NACC];

    const int t = threadIdx.x;            // column 0..383
    const int lane = t & 63;
    const int wv = t >> 6;
    const int bid = blockIdx.x;
    const int p = bid >> 2;               // plane
    const int s = bid & 3;                // strip
    const int y0 = s * STRIP_H;
    const float* __restrict__ xp = x + (size_t)p * HWSZ;

    const int W2S[3] = {3, 7, 15};        // l=0 -> w7, l=1 -> w15, l=2 -> w31
    int hi_i[3], lo_i[3];
    float lomul[3], invcx[3];
#pragma unroll
    for (int i = 0; i < 3; ++i) {
        int w2 = W2S[i];
        int hi = t + w2; if (hi > WW - 1) hi = WW - 1;
        int lo = t - w2 - 1;
        hi_i[i] = hi;
        lo_i[i] = lo < 0 ? 0 : lo;
        lomul[i] = lo < 0 ? 0.f : 1.f;
        int clo = t - w2; if (clo < 0) clo = 0;
        invcx[i] = 1.0f / (float)(hi - clo + 1);
    }

    auto hrow = [&](int r, int i) -> float {
        if ((unsigned)r >= (unsigned)HH) return 0.f;
        const float* row = ring[(r + RING) % RING];
        return row[hi_i[i]] - row[lo_i[i]] * lomul[i];
    };

    float bsum[3] = {0.f, 0.f, 0.f};
    float Aa[3] = {0.f, 0.f, 0.f};
    float Bb[3] = {0.f, 0.f, 0.f};
    float Cc[3] = {0.f, 0.f, 0.f};
    float T1 = 0.f, T2 = 0.f;

    // register prefetch of group-0 row (wave-private)
    float2 A0 = {0.f, 0.f}, A1 = {0.f, 0.f}, A2 = {0.f, 0.f};
    {
        int r = y0 - 16 + wv;
        if ((unsigned)r < (unsigned)HH) {
            const float* src = xp + (size_t)r * WW + lane * 6;
            A0 = *(const float2*)(src);
            A1 = *(const float2*)(src + 2);
            A2 = *(const float2*)(src + 4);
        }
    }

    for (int k = 0; k < NSUPER; ++k) {
        int r = y0 - 16 + 6 * k + wv;
        bool valid = (r <= y0 + 110) && ((unsigned)r < (unsigned)HH);
        if (valid) {
            float s0 = A0.x, s1 = s0 + A0.y, s2 = s1 + A1.x;
            float s3 = s2 + A1.y, s4 = s3 + A2.x, s5 = s4 + A2.y;
            float tot = s5, e = tot;
#pragma unroll
            for (int d = 1; d < 64; d <<= 1) {
                float u = __shfl_up(e, d, 64);
                if (lane >= d) e += u;
            }
            e -= tot;
            float* dst = &ring[r % RING][lane * 6];
            *(float2*)(dst)     = make_float2(s0 + e, s1 + e);
            *(float2*)(dst + 2) = make_float2(s2 + e, s3 + e);
            *(float2*)(dst + 4) = make_float2(s4 + e, s5 + e);
        }
        if (k < NSUPER - 1) {
            int rn = r + 6;
            if ((rn <= y0 + 110) && ((unsigned)rn < (unsigned)HH)) {
                const float* src = xp + (size_t)rn * WW + lane * 6;
                A0 = *(const float2*)(src);
                A1 = *(const float2*)(src + 2);
                A2 = *(const float2*)(src + 4);
            }
        }
        __syncthreads();

        int j = k - 6;
        if (j >= 0) {
            if (j == 0) {
#pragma unroll
                for (int i = 0; i < 3; ++i) {
                    int w2 = W2S[i];
                    float sum = 0.f;
                    for (int rr = y0 - w2; rr <= y0 + w2; ++rr) sum += hrow(rr, i);
                    bsum[i] = sum;
                }
            }
#pragma unroll
            for (int dy = 0; dy < 6; ++dy) {
                int y = y0 + 6 * j + dy;
                if (y > y0) {
#pragma unroll
                    for (int i = 0; i < 3; ++i) {
                        int w2 = W2S[i];
                        bsum[i] += hrow(y + w2, i) - hrow(y - w2 - 1, i);
                    }
                }
                const float* rowy = ring[(y + RING) % RING];
                int tm = t > 0 ? t - 1 : 0;
                float ph = rowy[t];
                float pl = rowy[tm];
                float xv = ph - (t > 0 ? pl : 0.f);
                T1 += xv;
                T2 = fmaf(xv, xv, T2);
#pragma unroll
                for (int i = 0; i < 3; ++i) {
                    int w2 = W2S[i];
                    int chi = y + w2; if (chi > HH - 1) chi = HH - 1;
                    int clo = y - w2; if (clo < 0) clo = 0;
                    float invcy = __builtin_amdgcn_rcpf((float)(chi - clo + 1));
                    float m = bsum[i] * (invcy * invcx[i]);
                    Aa[i] += m;
                    Bb[i] = fmaf(xv, m, Bb[i]);
                    Cc[i] = fmaf(m, m, Cc[i]);
                }
            }
        }
    }

    // deterministic block reduction of the 11 accumulators
    float acc[NACC] = {Aa[0], Bb[0], Cc[0], Aa[1], Bb[1], Cc[1],
                       Aa[2], Bb[2], Cc[2], T1, T2};
#pragma unroll
    for (int q = 0; q < NACC; ++q) {
#pragma unroll
        for (int d = 32; d >= 1; d >>= 1) acc[q] += __shfl_xor(acc[q], d, 64);
    }
    if (lane == 0) {
#pragma unroll
        for (int q = 0; q < NACC; ++q) redbuf[wv * NACC + q] = acc[q];
    }
    __syncthreads();
    if (t < NACC) {
        float ssum = 0.f;
#pragma unroll
        for (int w = 0; w < 6; ++w) ssum += redbuf[w * NACC + t];
        partials[bid * NACC + t] = ssum;
    }
}

// ---- per-(plane, l) std -> reciprocal scale; scales[op], op=(b*4+l)*64+c ----
__global__ __launch_bounds__(128) void scales_kernel(const float* __restrict__ partials,
                                                     const float* __restrict__ tiny,
                                                     float* __restrict__ scales) {
    int p = threadIdx.x;
    if (p >= NPLANES) return;
    int b = p >> 6, c = p & 63;
    float acc[NACC];
#pragma unroll
    for (int q = 0; q < NACC; ++q) acc[q] = 0.f;
    for (int s = 0; s < VSTRIPS; ++s) {
#pragma unroll
        for (int q = 0; q < NACC; ++q)
            acc[q] += partials[(p * VSTRIPS + s) * NACC + q];
    }
    const float Nf = (float)HWSZ;
    const float invNm1 = 1.0f / (float)(HWSZ - 1);
    float T1 = acc[9], T2 = acc[10];
    float thr = tiny[c] + 1e-6f;
#pragma unroll
    for (int l = 0; l < 4; ++l) {
        float S, Q;
        if (l < 3) {
            S = T1 - acc[l * 3 + 0];
            Q = T2 - 2.f * acc[l * 3 + 1] + acc[l * 3 + 2];
        } else {
            S = T1;     // var(x - mean(x)) == var(x)
            Q = T2;
        }
        float var = (Q - S * S / Nf) * invNm1;
        float sd = sqrtf(fmaxf(var, 0.f));
        sd = fmaxf(sd, thr);
        scales[(b * 4 + l) * CHN + c] = 1.0f / sd;
    }
}

// ---- out: persistent grid-stride; 1 coalesced read -> 4 coalesced store streams.
// 2048 blocks = 8/CU exactly; 9 fully-unrolled iters/thread with depth-1 prefetch.
__global__ __launch_bounds__(256) void out_kernel(const float* __restrict__ x,
                                                  const float* __restrict__ scales,
                                                  float* __restrict__ out) {
    __shared__ float ls[512];
    ls[threadIdx.x] = scales[threadIdx.x];
    ls[threadIdx.x + 256] = scales[threadIdx.x + 256];
    __syncthreads();

    const unsigned stride = OB * OT;                 // 524288
    const unsigned base = blockIdx.x * OT + threadIdx.x;
    const f4* __restrict__ xq = (const f4*)x;
    f4* __restrict__ oq = (f4*)out;

    f4 v = xq[base];
#pragma unroll
    for (int it = 0; it < OITER; ++it) {
        unsigned i = base + it * stride;
        f4 cur = v;
        if (it + 1 < OITER) v = xq[i + stride];      // prefetch next iter
        unsigned plane = i / QP;                     // wave-uniform (QP%64==0)
        unsigned q = i - plane * QP;
        unsigned b = plane >> 6, c = plane & 63;
        size_t o0 = (size_t)(b * 256 + c) * QP + q;  // l=0 output quad index
#pragma unroll
        for (int l = 0; l < 4; ++l) {
            float sc = ls[b * 256 + l * 64 + c];
            f4 o = cur * sc;
            oq[o0 + (size_t)l * 64 * QP] = o;
        }
    }
}

extern "C" void kernel_launch(void* const* d_in, const int* in_sizes, int n_in,
                              void* d_out, int out_size, void* d_ws, size_t ws_size,
                              hipStream_t stream) {
    const float* x = (const float*)d_in[0];
    const float* tiny = (const float*)d_in[1];
    float* out = (float*)d_out;

    float* partials = (float*)d_ws;                              // 512*11 floats
    float* scales = partials + NPLANES * VSTRIPS * NACC;         // 512 floats

    stats_fused<<<NPLANES * VSTRIPS, 384, 0, stream>>>(x, partials);
    scales_kernel<<<1, 128, 0, stream>>>(partials, tiny, scales);
    // Launched TWICE deliberately (idempotent): T - 211 isolates out-kernel cost
    // against the R3 baseline with zero model assumptions.
    out_kernel<<<OB, OT, 0, stream>>>(x, scales, out);
    out_kernel<<<OB, OT, 0, stream>>>(x, scales, out);
}

// Round 8
// 146.395 us; speedup vs baseline: 2.0953x; 2.0953x over previous
//
#include <hip/hip_runtime.h>

#define HH 384
#define WW 384
#define HWSZ (HH * WW)          // 147456
#define NPLANES 128             // 2 batch * 64 chan
#define CHN 64
#define VSTRIPS 4
#define STRIP_H 96              // HH / VSTRIPS
#define RING 48                 // LDS ring rows
#define RSTRIDE 416             // 16 left pad + 384 + 15 right pad (+1 align)
#define NACC 11
#define NSUPER 22               // 16 compute groups + 6 lag
#define QP (HWSZ / 4)           // 36864 float4 per plane
#define NINQ (NPLANES * QP)     // 4,718,592 input quads
#define OB 2048
#define OT 256
#define OITER (NINQ / (OB * OT))   // 9, exact

typedef float f4 __attribute__((ext_vector_type(4)));

// Ring row layout: [0..15]=0 (P[-k]), [16+c]=P[c], [400..414]=P[383].
// Boundary clamps of the four-corner box extraction become plain constant
// offsets: hrow(i) = row[16+t+w2] - row[15+t-w2]  (exact same values).
__global__ __launch_bounds__(384, 3) void stats_fused(const float* __restrict__ x,
                                                      float* __restrict__ partials) {
    __shared__ float ring[RING][RSTRIDE];   // 79,872 B
    __shared__ float redbuf[6 * NACC];

    const int t = threadIdx.x;              // column 0..383
    const int lane = t & 63;
    const int wv = t >> 6;
    const int bid = blockIdx.x;
    const int p = bid >> 2;                 // plane
    const int s = bid & 3;                  // strip
    const int y0 = s * STRIP_H;
    const float* __restrict__ xp = x + (size_t)p * HWSZ;

    const int W2S[3] = {3, 7, 15};          // l=0 -> w7, l=1 -> w15, l=2 -> w31
    float invcx[3];
#pragma unroll
    for (int i = 0; i < 3; ++i) {
        int w2 = W2S[i];
        int hi = t + w2; if (hi > WW - 1) hi = WW - 1;
        int lo = t - w2; if (lo < 0) lo = 0;
        invcx[i] = 1.0f / (float)(hi - lo + 1);
    }

    // zero the left pads once (staging never touches cols < 16)
    for (int idx = t; idx < RING * 16; idx += 384)
        ring[idx >> 4][idx & 15] = 0.f;

    float bsum[3] = {0.f, 0.f, 0.f};
    float Aa[3] = {0.f, 0.f, 0.f};
    float Bb[3] = {0.f, 0.f, 0.f};
    float Cc[3] = {0.f, 0.f, 0.f};
    float T1 = 0.f, T2 = 0.f;

    // register prefetch of group-0 row (wave-private)
    float2 A0 = {0.f, 0.f}, A1 = {0.f, 0.f}, A2 = {0.f, 0.f};
    {
        int r = y0 - 16 + wv;
        if ((unsigned)r < (unsigned)HH) {
            const float* src = xp + (size_t)r * WW + lane * 6;
            A0 = *(const float2*)(src);
            A1 = *(const float2*)(src + 2);
            A2 = *(const float2*)(src + 4);
        }
    }

    int by = 16;                            // ring slot of current compute row y0
    for (int k = 0; k < NSUPER; ++k) {
        const int u = 6 * k + wv;           // slot sequence 0..131
        const int r = y0 - 16 + u;          // absolute row
        int slot = u;
        if (slot >= 96) slot -= 96; else if (slot >= 48) slot -= 48;

        if (u <= 126) {                     // r <= y0+110: this slot will be read
            float* dst = ring[slot];
            if ((unsigned)r < (unsigned)HH) {
                float s0 = A0.x, s1 = s0 + A0.y, s2 = s1 + A1.x;
                float s3 = s2 + A1.y, s4 = s3 + A2.x, s5 = s4 + A2.y;
                float tot = s5, e = tot;
#pragma unroll
                for (int d = 1; d < 64; d <<= 1) {
                    float uu = __shfl_up(e, d, 64);
                    if (lane >= d) e += uu;
                }
                e -= tot;                   // exclusive offset of lane totals
                float p383 = __shfl(s5 + e, 63, 64);
                float* dp = dst + 16 + lane * 6;
                *(float2*)(dp)     = make_float2(s0 + e, s1 + e);
                *(float2*)(dp + 2) = make_float2(s2 + e, s3 + e);
                *(float2*)(dp + 4) = make_float2(s4 + e, s5 + e);
                if (lane < 15) dst[400 + lane] = p383;   // right pad = P[383]
            } else {
                // zero row (outside image): cols + right pad
                float* dp = dst + 16 + lane * 6;
                *(float2*)(dp)     = make_float2(0.f, 0.f);
                *(float2*)(dp + 2) = make_float2(0.f, 0.f);
                *(float2*)(dp + 4) = make_float2(0.f, 0.f);
                if (lane < 15) dst[400 + lane] = 0.f;
            }
        }
        // issue next group's loads now; complete under compute phase
        if (k < NSUPER - 1) {
            int rn = r + 6;
            if (u + 6 <= 126 && (unsigned)rn < (unsigned)HH) {
                const float* src = xp + (size_t)rn * WW + lane * 6;
                A0 = *(const float2*)(src);
                A1 = *(const float2*)(src + 2);
                A2 = *(const float2*)(src + 4);
            }
        }
        __syncthreads();                    // one barrier per superstep

        int j = k - 6;
        if (j >= 0) {
            if (j == 0) {                   // prime vertical box sums at y = y0
#pragma unroll
                for (int i = 0; i < 3; ++i) {
                    int w2 = W2S[i];
                    float sum = 0.f;
                    for (int rr = -w2; rr <= w2; ++rr) {
                        const float* pr = &ring[16 + rr][t];  // slot 1..31, no wrap
                        sum += pr[16 + w2] - pr[15 - w2];
                    }
                    bsum[i] = sum;
                }
            }
#pragma unroll
            for (int dy = 0; dy < 6; ++dy) {
                int y = y0 + 6 * j + dy;
                if (j > 0 || dy > 0) {
                    // enter slots by+w2, leave slots by-(w2+1), single cond wrap
                    int e0 = by + 3;  if (e0 >= RING) e0 -= RING;
                    int e1 = by + 7;  if (e1 >= RING) e1 -= RING;
                    int e2 = by + 15; if (e2 >= RING) e2 -= RING;
                    int l0 = by - 4;  if (l0 < 0) l0 += RING;
                    int l1 = by - 8;  if (l1 < 0) l1 += RING;
                    int l2 = by - 16; if (l2 < 0) l2 += RING;
                    const float* pe0 = &ring[e0][t];
                    const float* pe1 = &ring[e1][t];
                    const float* pe2 = &ring[e2][t];
                    const float* pl0 = &ring[l0][t];
                    const float* pl1 = &ring[l1][t];
                    const float* pl2 = &ring[l2][t];
                    bsum[0] += (pe0[19] - pe0[12]) - (pl0[19] - pl0[12]);
                    bsum[1] += (pe1[23] - pe1[8])  - (pl1[23] - pl1[8]);
                    bsum[2] += (pe2[31] - pe2[0])  - (pl2[31] - pl2[0]);
                }
                const float* pr = &ring[by][t];
                float xv = pr[16] - pr[15];         // recover x[y][t]
                T1 += xv;
                T2 = fmaf(xv, xv, T2);
#pragma unroll
                for (int i = 0; i < 3; ++i) {
                    int w2 = W2S[i];
                    int chi = y + w2; if (chi > HH - 1) chi = HH - 1;
                    int clo = y - w2; if (clo < 0) clo = 0;
                    float invcy = __builtin_amdgcn_rcpf((float)(chi - clo + 1));
                    float m = bsum[i] * (invcy * invcx[i]);
                    Aa[i] += m;
                    Bb[i] = fmaf(xv, m, Bb[i]);
                    Cc[i] = fmaf(m, m, Cc[i]);
                }
                ++by; if (by >= RING) by = 0;
            }
        }
    }

    // deterministic block reduction of the 11 accumulators
    float acc[NACC] = {Aa[0], Bb[0], Cc[0], Aa[1], Bb[1], Cc[1],
                       Aa[2], Bb[2], Cc[2], T1, T2};
#pragma unroll
    for (int q = 0; q < NACC; ++q) {
#pragma unroll
        for (int d = 32; d >= 1; d >>= 1) acc[q] += __shfl_xor(acc[q], d, 64);
    }
    if (lane == 0) {
#pragma unroll
        for (int q = 0; q < NACC; ++q) redbuf[wv * NACC + q] = acc[q];
    }
    __syncthreads();
    if (t < NACC) {
        float ssum = 0.f;
#pragma unroll
        for (int w = 0; w < 6; ++w) ssum += redbuf[w * NACC + t];
        partials[bid * NACC + t] = ssum;
    }
}

// ---- per-(plane, l) std -> reciprocal scale; scales[op], op=(b*4+l)*64+c ----
__global__ __launch_bounds__(128) void scales_kernel(const float* __restrict__ partials,
                                                     const float* __restrict__ tiny,
                                                     float* __restrict__ scales) {
    int p = threadIdx.x;
    if (p >= NPLANES) return;
    int b = p >> 6, c = p & 63;
    float acc[NACC];
#pragma unroll
    for (int q = 0; q < NACC; ++q) acc[q] = 0.f;
    for (int s = 0; s < VSTRIPS; ++s) {
#pragma unroll
        for (int q = 0; q < NACC; ++q)
            acc[q] += partials[(p * VSTRIPS + s) * NACC + q];
    }
    const float Nf = (float)HWSZ;
    const float invNm1 = 1.0f / (float)(HWSZ - 1);
    float T1 = acc[9], T2 = acc[10];
    float thr = tiny[c] + 1e-6f;
#pragma unroll
    for (int l = 0; l < 4; ++l) {
        float S, Q;
        if (l < 3) {
            S = T1 - acc[l * 3 + 0];
            Q = T2 - 2.f * acc[l * 3 + 1] + acc[l * 3 + 2];
        } else {
            S = T1;     // var(x - mean(x)) == var(x)
            Q = T2;
        }
        float var = (Q - S * S / Nf) * invNm1;
        float sd = sqrtf(fmaxf(var, 0.f));
        sd = fmaxf(sd, thr);
        scales[(b * 4 + l) * CHN + c] = 1.0f / sd;
    }
}

// ---- out: persistent grid-stride, 1 coalesced read -> 4 nontemporal store streams ----
__global__ __launch_bounds__(256) void out_kernel(const float* __restrict__ x,
                                                  const float* __restrict__ scales,
                                                  float* __restrict__ out) {
    __shared__ float ls[512];
    ls[threadIdx.x] = scales[threadIdx.x];
    ls[threadIdx.x + 256] = scales[threadIdx.x + 256];
    __syncthreads();

    const unsigned stride = OB * OT;                 // 524288
    const unsigned base = blockIdx.x * OT + threadIdx.x;
    const f4* __restrict__ xq = (const f4*)x;
    f4* __restrict__ oq = (f4*)out;

    f4 v = xq[base];
#pragma unroll
    for (int it = 0; it < OITER; ++it) {
        unsigned i = base + it * stride;
        f4 cur = v;
        if (it + 1 < OITER) v = xq[i + stride];      // prefetch next iter
        unsigned plane = i / QP;                     // wave-uniform (QP%64==0)
        unsigned q = i - plane * QP;
        unsigned b = plane >> 6, c = plane & 63;
        size_t o0 = (size_t)(b * 256 + c) * QP + q;  // l=0 output quad index
#pragma unroll
        for (int l = 0; l < 4; ++l) {
            f4 o = cur * ls[b * 256 + l * 64 + c];
            __builtin_nontemporal_store(o, oq + o0 + (size_t)l * 64 * QP);
        }
    }
}

extern "C" void kernel_launch(void* const* d_in, const int* in_sizes, int n_in,
                              void* d_out, int out_size, void* d_ws, size_t ws_size,
                              hipStream_t stream) {
    const float* x = (const float*)d_in[0];
    const float* tiny = (const float*)d_in[1];
    float* out = (float*)d_out;

    float* partials = (float*)d_ws;                              // 512*11 floats
    float* scales = partials + NPLANES * VSTRIPS * NACC;         // 512 floats

    stats_fused<<<NPLANES * VSTRIPS, 384, 0, stream>>>(x, partials);
    scales_kernel<<<1, 128, 0, stream>>>(partials, tiny, scales);
    out_kernel<<<OB, OT, 0, stream>>>(x, scales, out);
}